// Round 12
// baseline (1588.446 us; speedup 1.0000x reference)
//
#include <hip/hip_runtime.h>
#include <hip/hip_bf16.h>

#define NPT 2048
#define NB 8
#define KNN 20

__device__ __forceinline__ float bf2f(unsigned short u) {
    return __uint_as_float(((unsigned)u) << 16);
}
__device__ __forceinline__ unsigned short f2bf(float f) {
    unsigned u = __float_as_uint(f);
    unsigned lsb = (u >> 16) & 1u;
    u += 0x7fffu + lsb;
    return (unsigned short)(u >> 16);
}
__device__ __forceinline__ float lrelu(float x) { return x >= 0.f ? x : 0.2f * x; }
__device__ __forceinline__ float ldin(const void* p, size_t i, bool f32) {
    return f32 ? ((const float*)p)[i] : bf2f(((const unsigned short*)p)[i]);
}
__device__ __forceinline__ float rfl(float x) {
    return __int_as_float(__builtin_amdgcn_readfirstlane(__float_as_int(x)));
}
// 64-bit sortable key: FULL ordered-fp32 distance in bits [42:11], low 11 bits
// = 2047-m (tie -> lower index). Unique keys; strict-descending selection
// reproduces jax top_k (value desc, index asc) exactly. 0 = empty sentinel.
__device__ __forceinline__ unsigned long long mkkey64(float d, int m) {
    unsigned u = __float_as_uint(d);
    unsigned p = u ^ (unsigned)(((int)u >> 31) | 0x80000000);
    return ((unsigned long long)p << 11) | (unsigned)(2047 - m);
}
__device__ __forceinline__ unsigned long long shfl_xor_u64(unsigned long long v, int off) {
    unsigned lo = (unsigned)__shfl_xor((int)(unsigned)(v & 0xFFFFFFFFull), off);
    unsigned hi = (unsigned)__shfl_xor((int)(unsigned)(v >> 32), off);
    return ((unsigned long long)hi << 32) | lo;
}

// Top-KNN selection over 32 distances/lane (key recomputed on the fly from
// slot geometry m = (s>>SH)*STR + lane*LM + (s&MK)); per-lane top-2 buffer.
template<int SH, int STR, int LM, int MK>
__device__ __forceinline__ void select_topk_d(const float* __restrict__ d, int lane, int* mymp) {
    unsigned long long b1 = 0ull, b2 = 0ull;
    #pragma unroll
    for (int s = 0; s < 32; s++) {
        int m = (s >> SH)*STR + lane*LM + (s & MK);
        unsigned long long v = mkkey64(d[s], m);
        bool gt1 = v > b1;
        unsigned long long nb2 = gt1 ? b1 : (v > b2 ? v : b2);
        b1 = gt1 ? v : b1;
        b2 = nb2;
    }
    unsigned long long lastpop = ~0ull;
    int mym = 0;
    #pragma unroll 1
    for (int k = 0; k < KNN; k++) {
        unsigned long long best = b1;
        #pragma unroll
        for (int off = 32; off > 0; off >>= 1) {
            unsigned long long o = shfl_xor_u64(best, off);
            best = o > best ? o : best;
        }
        if (lane == k) mym = 2047 - (int)(best & 2047ull);
        bool won = (b1 == best) && (best != 0ull);
        if (won) { lastpop = b1; b1 = b2; b2 = 0ull; }
        bool dirty = won && (b1 == 0ull);
        if (__ballot(dirty)) {
            if (dirty) {
                unsigned long long n1 = 0ull, n2 = 0ull;
                #pragma unroll
                for (int s = 0; s < 32; s++) {
                    int m = (s >> SH)*STR + lane*LM + (s & MK);
                    unsigned long long v = mkkey64(d[s], m);
                    v = (v < lastpop) ? v : 0ull;
                    bool gt1 = v > n1;
                    unsigned long long t2 = gt1 ? n1 : (v > n2 ? v : n2);
                    n1 = gt1 ? v : n1;
                    n2 = t2;
                }
                b1 = n1; b2 = n2;
            }
        }
    }
    *mymp = mym;
}

// ---------------- workspace layout (float units), liveness-overlapped ----------------
constexpr size_t F_IDX1  = 0;
constexpr size_t F_IDX2  = 327680;
constexpr size_t F_WT    = 655360;
constexpr size_t F_XCATT = 983040;     // (B,N,192) -> 4128768
constexpr size_t F_XCAT  = 4128768;    // (B,192,N) -> 7274496
constexpr size_t F_GPART = 7274496;
constexpr size_t F_G     = 7405568;
constexpr size_t F_V7P   = 7413760;
constexpr size_t F_V7    = 7430144;
constexpr size_t F_WP    = 7432192;    // -> 8074048
constexpr size_t F_FLAG  = 8074048;
constexpr size_t F_XX    = 8074052;    // (B,2048) column norms -> 8090436
constexpr size_t F_X7    = 0;          // bf16 (B,256,N) over dead idx/wt/xcatT-head
constexpr size_t F_X8    = 2097152;    // bf16 (B,256,N)
constexpr size_t F_X9    = 4194304;    // bf16 (B,128,N) over dead xcat
constexpr size_t F_TOTAL = 8090436;

constexpr size_t P_AMP1 = 0;
constexpr size_t P_BMP1 = 64;
constexpr size_t P_AMP2 = 128;
constexpr size_t P_BMP2 = 192;
constexpr size_t P_AMP3 = 256;
constexpr size_t P_BMP3 = 320;
constexpr size_t P_W1   = 384;
constexpr size_t P_B1   = 896;
constexpr size_t P_W2   = 960;
constexpr size_t P_B2   = 5056;
constexpr size_t P_W3A  = 5120;
constexpr size_t P_W3B  = 9216;
constexpr size_t P_B3   = 13312;
constexpr size_t P_W4   = 13376;
constexpr size_t P_B4   = 17472;
constexpr size_t P_W5A  = 17536;
constexpr size_t P_W5B  = 21632;
constexpr size_t P_B5   = 25728;
constexpr size_t P_W6   = 25792;
constexpr size_t P_B6   = 222400;
constexpr size_t P_W7A  = 223424;
constexpr size_t P_W7B  = 485568;
constexpr size_t P_B7   = 534720;
constexpr size_t P_W8   = 534976;
constexpr size_t P_B8   = 600512;
constexpr size_t P_W9   = 600768;
constexpr size_t P_B9   = 633536;
constexpr size_t P_W10  = 633664;

struct InPtrs { const void* p[38]; };

__global__ __launch_bounds__(256) void zero_out_kernel(unsigned short* out, int nelem) {
    int i = blockIdx.x * 256 + threadIdx.x;
    if (i < nelem) out[i] = 0;
}

// ---------------- dtype detection (even ushorts: fp32 low-mantissa halves) ----------------
__global__ __launch_bounds__(256) void detect_kernel(const unsigned short* __restrict__ u,
                                                     int* __restrict__ flag) {
    __shared__ int red[256];
    int tid = threadIdx.x;
    int cnt = 0;
    for (int i = tid * 2; i < 98304; i += 512) {
        unsigned e = (u[i] >> 7) & 0xFFu;
        cnt += (e == 0xFFu) ? 1 : 0;
    }
    red[tid] = cnt;
    __syncthreads();
    for (int s = 128; s > 0; s >>= 1) {
        if (tid < s) red[tid] += red[tid + s];
        __syncthreads();
    }
    if (tid == 0) flag[0] = (red[0] > 8) ? 1 : 0;
}

// ---------------- weight prep ----------------
__global__ __launch_bounds__(256) void prep_kernel(InPtrs in, float* __restrict__ wp,
                                                   const int* __restrict__ dflag) {
    bool f32 = dflag[0] != 0;
    int gtid = blockIdx.x * 256 + threadIdx.x;
    int gstr = gridDim.x * 256;
    if (gtid < 192) {
        int which = gtid >> 6, o = gtid & 63;
        const void *w, *s, *bb; int cin, cout; size_t ao, bo;
        if (which == 0)      { w = in.p[1]; s = in.p[2]; bb = in.p[3]; cin = 3;  cout = 3;  ao = P_AMP1; bo = P_BMP1; }
        else if (which == 1) { w = in.p[4]; s = in.p[5]; bb = in.p[6]; cin = 64; cout = 64; ao = P_AMP2; bo = P_BMP2; }
        else                 { w = in.p[7]; s = in.p[8]; bb = in.p[9]; cin = 64; cout = 64; ao = P_AMP3; bo = P_BMP3; }
        if (o < cout) {
            float sum = 0.f;
            for (int c = 0; c < cin; c++) sum += ldin(w, o*cin + c, f32);
            wp[ao + o] = sum * ldin(s, o, f32);
            wp[bo + o] = ldin(bb, o, f32);
        }
    }
    for (int i = gtid; i < 512; i += gstr) {
        int q = i & 3, o = (i >> 2) & 63, cc = i >> 8, c = cc*4 + q;
        wp[P_W1 + i] = (c < 6) ? ldin(in.p[10], o*6 + c, f32) * ldin(in.p[11], o, f32) : 0.f;
    }
    for (int i = gtid; i < 64; i += gstr) wp[P_B1 + i] = ldin(in.p[12], i, f32);
    for (int i = gtid; i < 4096; i += gstr) {
        int q = i & 3, o = (i >> 2) & 63, cc = i >> 8;
        wp[P_W2 + i] = ldin(in.p[13], o*64 + cc*4 + q, f32) * ldin(in.p[14], o, f32);
    }
    for (int i = gtid; i < 64; i += gstr) wp[P_B2 + i] = ldin(in.p[15], i, f32);
    for (int i = gtid; i < 4096; i += gstr) {
        int q = i & 3, o = (i >> 2) & 63, cc = i >> 8;
        float sc = ldin(in.p[17], o, f32);
        wp[P_W3A + i] = ldin(in.p[16], o*128 + cc*4 + q, f32) * sc;
        wp[P_W3B + i] = ldin(in.p[16], o*128 + 64 + cc*4 + q, f32) * sc;
    }
    for (int i = gtid; i < 64; i += gstr) wp[P_B3 + i] = ldin(in.p[18], i, f32);
    for (int i = gtid; i < 4096; i += gstr) {
        int q = i & 3, o = (i >> 2) & 63, cc = i >> 8;
        wp[P_W4 + i] = ldin(in.p[19], o*64 + cc*4 + q, f32) * ldin(in.p[20], o, f32);
    }
    for (int i = gtid; i < 64; i += gstr) wp[P_B4 + i] = ldin(in.p[21], i, f32);
    for (int i = gtid; i < 4096; i += gstr) {
        int q = i & 3, o = (i >> 2) & 63, cc = i >> 8;
        float sc = ldin(in.p[23], o, f32);
        wp[P_W5A + i] = ldin(in.p[22], o*128 + cc*4 + q, f32) * sc;
        wp[P_W5B + i] = ldin(in.p[22], o*128 + 64 + cc*4 + q, f32) * sc;
    }
    for (int i = gtid; i < 64; i += gstr) wp[P_B5 + i] = ldin(in.p[24], i, f32);
    for (int i = gtid; i < 192*1024; i += gstr) {
        int o = i & 1023, c = i >> 10;
        wp[P_W6 + i] = ldin(in.p[25], o*192 + c, f32) * ldin(in.p[26], o, f32);
    }
    for (int i = gtid; i < 1024; i += gstr) wp[P_B6 + i] = ldin(in.p[27], i, f32);
    for (int i = gtid; i < 1024*256; i += gstr) {
        int o = i & 255, c = i >> 8;
        wp[P_W7A + i] = ldin(in.p[28], o*1216 + c, f32) * ldin(in.p[29], o, f32);
    }
    for (int i = gtid; i < 192*256; i += gstr) {
        int o = i & 255, c = i >> 8;
        wp[P_W7B + i] = ldin(in.p[28], o*1216 + 1024 + c, f32) * ldin(in.p[29], o, f32);
    }
    for (int i = gtid; i < 256; i += gstr) wp[P_B7 + i] = ldin(in.p[30], i, f32);
    for (int i = gtid; i < 256*256; i += gstr) {
        int o = i & 255, c = i >> 8;
        wp[P_W8 + i] = ldin(in.p[31], o*256 + c, f32) * ldin(in.p[32], o, f32);
    }
    for (int i = gtid; i < 256; i += gstr) wp[P_B8 + i] = ldin(in.p[33], i, f32);
    for (int i = gtid; i < 256*128; i += gstr) {
        int o = i & 127, c = i >> 7;
        wp[P_W9 + i] = ldin(in.p[34], o*256 + c, f32) * ldin(in.p[35], o, f32);
    }
    for (int i = gtid; i < 128; i += gstr) wp[P_B9 + i] = ldin(in.p[36], i, f32);
    for (int i = gtid; i < 128*64; i += gstr) {
        int o = i & 63, c = i >> 6;
        wp[P_W10 + i] = (o < 50) ? ldin(in.p[37], o*128 + c, f32) : 0.f;
    }
}

// ---------------- xyz KNN + manifold weight ----------------
__global__ __launch_bounds__(256) void knn_xyz_kernel(const void* __restrict__ xin,
                                                      const int* __restrict__ dflag,
                                                      int* __restrict__ idx_out,
                                                      float* __restrict__ wt_out) {
    bool f32 = dflag[0] != 0;
    int lane = threadIdx.x & 63, wid = threadIdx.x >> 6;
    int p = blockIdx.x * 4 + wid;
    int b = p >> 11, n = p & 2047;
    size_t eb = (size_t)b * 6 * NPT;
    float cx0 = ldin(xin, eb + n, f32), cx1 = ldin(xin, eb + NPT + n, f32), cx2 = ldin(xin, eb + 2*NPT + n, f32);
    float xxn = __builtin_fmaf(cx2, cx2, __builtin_fmaf(cx1, cx1, cx0*cx0));
    float d[32];
    #pragma unroll
    for (int j4 = 0; j4 < 8; j4++) {
        int m0 = j4*256 + lane*4;
        float x0q[4], x1q[4], x2q[4];
        if (f32) {
            const float* xf = (const float*)xin + eb;
            float4 a0 = *(const float4*)(xf + m0);
            float4 a1 = *(const float4*)(xf + NPT + m0);
            float4 a2 = *(const float4*)(xf + 2*NPT + m0);
            x0q[0]=a0.x; x0q[1]=a0.y; x0q[2]=a0.z; x0q[3]=a0.w;
            x1q[0]=a1.x; x1q[1]=a1.y; x1q[2]=a1.z; x1q[3]=a1.w;
            x2q[0]=a2.x; x2q[1]=a2.y; x2q[2]=a2.z; x2q[3]=a2.w;
        } else {
            const unsigned short* xu = (const unsigned short*)xin + eb;
            ushort4 a0 = *(const ushort4*)(xu + m0);
            ushort4 a1 = *(const ushort4*)(xu + NPT + m0);
            ushort4 a2 = *(const ushort4*)(xu + 2*NPT + m0);
            x0q[0]=bf2f(a0.x); x0q[1]=bf2f(a0.y); x0q[2]=bf2f(a0.z); x0q[3]=bf2f(a0.w);
            x1q[0]=bf2f(a1.x); x1q[1]=bf2f(a1.y); x1q[2]=bf2f(a1.z); x1q[3]=bf2f(a1.w);
            x2q[0]=bf2f(a2.x); x2q[1]=bf2f(a2.y); x2q[2]=bf2f(a2.z); x2q[3]=bf2f(a2.w);
        }
        #pragma unroll
        for (int q = 0; q < 4; q++) {
            float x0 = x0q[q], x1 = x1q[q], x2 = x2q[q];
            float inner = __builtin_fmaf(x2, cx2, __builtin_fmaf(x1, cx1, x0*cx0));
            float xxm   = __builtin_fmaf(x2, x2,  __builtin_fmaf(x1, x1,  x0*x0));
            d[j4*4 + q] = __builtin_fmaf(2.f, inner, -xxn) - xxm;
        }
    }
    int mym;
    select_topk_d<2,256,4,3>(d, lane, &mym);
    if (lane < KNN) idx_out[(size_t)p*KNN + lane] = mym;
    int m0n = __shfl(mym, 0);
    if (lane < KNN) {
        size_t nb0 = eb + 3*NPT;
        float c0 = ldin(xin, nb0 + m0n, f32), c1 = ldin(xin, nb0 + NPT + m0n, f32), c2 = ldin(xin, nb0 + 2*NPT + m0n, f32);
        float g0 = ldin(xin, nb0 + mym, f32), g1 = ldin(xin, nb0 + NPT + mym, f32), g2 = ldin(xin, nb0 + 2*NPT + mym, f32);
        float cn = sqrtf(__builtin_fmaf(c2, c2, __builtin_fmaf(c1, c1, c0*c0)));
        float gn = sqrtf(__builtin_fmaf(g2, g2, __builtin_fmaf(g1, g1, g0*g0)));
        float num = __builtin_fmaf(c2, g2, __builtin_fmaf(c1, g1, c0*g0));
        wt_out[(size_t)p*KNN + lane] = num / fmaxf(cn * gn, 1e-8f);
    }
}

// ---------------- column norms for feature KNN ----------------
__global__ __launch_bounds__(512) void norms_kernel(const float* __restrict__ xcat, int inRow,
                                                    float* __restrict__ xxg) {
    int t = blockIdx.x * 512 + threadIdx.x;   // 16384
    int b = t >> 11, m = t & 2047;
    const float* xb = xcat + ((size_t)b*192 + inRow) * NPT + m;
    float s = 0.f;
    #pragma unroll
    for (int c = 0; c < 64; c++) { float v = xb[(size_t)c*NPT]; s = __builtin_fmaf(v, v, s); }
    xxg[t] = s;
}

// ---------------- feature-space KNN (C=64): 1 query/wave, SGPR query, d-float sel ----------------
__global__ __launch_bounds__(512) void knn_feat_kernel(const float* __restrict__ xcat,
        const float* __restrict__ xcatT, const float* __restrict__ xxg,
        int inOff, int* __restrict__ idx_out) {
    __shared__ float xmL[64][132];
    int tid = threadIdx.x, lane = tid & 63, wid = tid >> 6;
    int p = blockIdx.x * 8 + wid;
    int b = p >> 11, n = p & 2047;
    const float* xb = xcat + ((size_t)b*192 + inOff) * NPT;
    const float* qg = xcatT + ((size_t)(b*NPT + n))*192 + inOff;
    float q[64];
    #pragma unroll
    for (int c4 = 0; c4 < 16; c4++) {
        float4 v = *(const float4*)(qg + c4*4);
        q[c4*4+0] = rfl(v.x); q[c4*4+1] = rfl(v.y);
        q[c4*4+2] = rfl(v.z); q[c4*4+3] = rfl(v.w);
    }
    float xxn = xxg[b*2048 + n];
    float d[32];
    #pragma unroll
    for (int ch = 0; ch < 16; ch++) {
        __syncthreads();
        #pragma unroll
        for (int i = 0; i < 4; i++) {
            int idx4 = tid + i*512;
            int c = idx4 >> 5, m4 = (idx4 & 31) * 4;
            *(float4*)&xmL[c][m4] = *(const float4*)(xb + (size_t)c*NPT + ch*128 + m4);
        }
        __syncthreads();
        float in0 = 0.f, in1 = 0.f;
        #pragma unroll
        for (int c = 0; c < 64; c++) {
            float2 v = *(const float2*)&xmL[c][2*lane];
            in0 = __builtin_fmaf(q[c], v.x, in0);
            in1 = __builtin_fmaf(q[c], v.y, in1);
        }
        float2 xxv = *(const float2*)&xxg[b*2048 + ch*128 + 2*lane];
        d[ch*2]   = __builtin_fmaf(2.f, in0, -xxn) - xxv.x;
        d[ch*2+1] = __builtin_fmaf(2.f, in1, -xxn) - xxv.y;
    }
    int mym;
    select_topk_d<1,128,2,1>(d, lane, &mym);
    if (lane < KNN) idx_out[(size_t)p*KNN + lane] = mym;
}

// ---------------- stage 1 (xyz edge conv -> x1), 1 wave/block, barrier-free ----------------
__global__ __launch_bounds__(64) void stage1_kernel(const void* __restrict__ xin,
        const int* __restrict__ dflag,
        const int* __restrict__ idxb, const float* __restrict__ wtb,
        const float* __restrict__ wp, float* __restrict__ xcat, float* __restrict__ xcatT) {
    __shared__ float y1L[KNN][64];
    bool f32 = dflag[0] != 0;
    int lane = threadIdx.x & 63;
    int p = blockIdx.x, b = p >> 11, n = p & 2047;
    size_t eb = (size_t)b * 6 * NPT;
    int myidx = 0; float mywt = 0.f;
    if (lane < KNN) {
        myidx = idxb[(size_t)p*KNN + lane] & 2047;
        mywt  = wtb[(size_t)p*KNN + lane];
    }
    float cx0 = ldin(xin, eb + n, f32), cx1 = ldin(xin, eb + NPT + n, f32), cx2 = ldin(xin, eb + 2*NPT + n, f32);
    float aM0 = wp[P_AMP1+0], aM1 = wp[P_AMP1+1], aM2 = wp[P_AMP1+2];
    float bM0 = wp[P_BMP1+0], bM1 = wp[P_BMP1+1], bM2 = wp[P_BMP1+2];
    float w1r[8];
    #pragma unroll
    for (int cc = 0; cc < 2; cc++) {
        float4 v = *(const float4*)&wp[P_W1 + (size_t)(cc*64 + lane)*4];
        w1r[cc*4+0] = v.x; w1r[cc*4+1] = v.y; w1r[cc*4+2] = v.z; w1r[cc*4+3] = v.w;
    }
    float b1v = wp[P_B1 + lane];
    #pragma unroll
    for (int k = 0; k < KNN; k++) {
        int m = __shfl(myidx, k);
        float w = __shfl(mywt, k);
        float n0 = ldin(xin, eb + m, f32), n1 = ldin(xin, eb + NPT + m, f32), n2 = ldin(xin, eb + 2*NPT + m, f32);
        float h0 = (n0 - cx0) * lrelu(fmaf(aM0, w, bM0));
        float h1 = (n1 - cx1) * lrelu(fmaf(aM1, w, bM1));
        float h2 = (n2 - cx2) * lrelu(fmaf(aM2, w, bM2));
        float acc = w1r[0]*h0 + w1r[1]*h1 + w1r[2]*h2 + w1r[3]*cx0 + w1r[4]*cx1 + w1r[5]*cx2;
        y1L[k][lane] = lrelu(acc + b1v);   // same-wave LDS: DS pipe in-order, no barrier
    }
    float acc2[KNN];
    #pragma unroll
    for (int k = 0; k < KNN; k++) acc2[k] = 0.f;
    #pragma unroll
    for (int cc = 0; cc < 16; cc++) {
        float4 w4 = *(const float4*)&wp[P_W2 + (size_t)(cc*64 + lane)*4];
        #pragma unroll
        for (int k = 0; k < KNN; k++) {
            float4 h4 = *(const float4*)&y1L[k][cc*4];
            float a = acc2[k];
            a = fmaf(w4.x, h4.x, a); a = fmaf(w4.y, h4.y, a);
            a = fmaf(w4.z, h4.z, a); a = fmaf(w4.w, h4.w, a);
            acc2[k] = a;
        }
    }
    float b2v = wp[P_B2 + lane];
    float mx = -1e38f;
    #pragma unroll
    for (int k = 0; k < KNN; k++) mx = fmaxf(mx, lrelu(acc2[k] + b2v));
    xcat[((size_t)b*192 + lane)*NPT + n] = mx;
    xcatT[((size_t)(b*NPT + n))*192 + lane] = mx;
}

// ---------------- stages 2/3: 2 points/wave, k-chunked (4), barrier-free ----------------
__global__ __launch_bounds__(64) void stage23_kernel(
        const float* __restrict__ xcatT, const int* __restrict__ idxb, const float* __restrict__ wtb,
        const float* __restrict__ wp,
        int aOff, int bmpOff, int WaOff, int WbOff, int biasOff,
        int W2Off, int bias2Off, int inOff, int outCh, int second,
        float* __restrict__ xcat, float* __restrict__ xcatTo) {
    __shared__ float hL[2][4][64];
    __shared__ float cL[2][64];
    int lane = threadIdx.x & 63;
    int p0 = blockIdx.x * 2, p1 = p0 + 1;
    int b = p0 >> 11, n0 = p0 & 2047, n1 = n0 + 1;   // p0 even -> same batch
    const float* xTb = xcatT + (size_t)b * NPT * 192 + inOff;
    int id0 = 0, id1 = 0; float wt0 = 0.f, wt1 = 0.f;
    if (lane < KNN) {
        id0 = idxb[(size_t)p0*KNN + lane] & 2047;
        wt0 = wtb[(size_t)p0*KNN + lane];
        id1 = idxb[(size_t)p1*KNN + lane] & 2047;
        wt1 = wtb[(size_t)p1*KNN + lane];
    }
    float cv0 = xTb[(size_t)n0 * 192 + lane];
    float cv1 = xTb[(size_t)n1 * 192 + lane];
    cL[0][lane] = cv0;
    cL[1][lane] = cv1;
    float aMP = wp[aOff + lane], bMP = wp[bmpOff + lane];
    float bv = wp[biasOff + lane];
    float b2v = second ? wp[bias2Off + lane] : 0.f;
    // center-half contribution vb (once per point)
    float vb0 = 0.f, vb1 = 0.f;
    #pragma unroll
    for (int cc = 0; cc < 16; cc++) {
        float4 w4 = *(const float4*)&wp[WbOff + (size_t)(cc*64 + lane)*4];
        float4 c40 = *(const float4*)&cL[0][cc*4];
        float4 c41 = *(const float4*)&cL[1][cc*4];
        vb0 = fmaf(w4.x, c40.x, vb0); vb0 = fmaf(w4.y, c40.y, vb0);
        vb0 = fmaf(w4.z, c40.z, vb0); vb0 = fmaf(w4.w, c40.w, vb0);
        vb1 = fmaf(w4.x, c41.x, vb1); vb1 = fmaf(w4.y, c41.y, vb1);
        vb1 = fmaf(w4.z, c41.z, vb1); vb1 = fmaf(w4.w, c41.w, vb1);
    }
    float mx0 = -1e38f, mx1 = -1e38f;
    #pragma unroll 1
    for (int kc = 0; kc < KNN; kc += 4) {
        // gather+transform: 8 independent scattered row loads in flight
        #pragma unroll
        for (int j = 0; j < 4; j++) {
            int k = kc + j;
            int m0 = __shfl(id0, k); float w0 = __shfl(wt0, k);
            int m1 = __shfl(id1, k); float w1 = __shfl(wt1, k);
            float nb0 = xTb[(size_t)m0 * 192 + lane];
            float nb1 = xTb[(size_t)m1 * 192 + lane];
            hL[0][j][lane] = (nb0 - cv0) * lrelu(fmaf(aMP, w0, bMP));
            hL[1][j][lane] = (nb1 - cv1) * lrelu(fmaf(aMP, w1, bMP));
        }
        float a0[4], a1[4];
        #pragma unroll
        for (int j = 0; j < 4; j++) { a0[j] = 0.f; a1[j] = 0.f; }
        #pragma unroll
        for (int cc = 0; cc < 16; cc++) {
            float4 w4 = *(const float4*)&wp[WaOff + (size_t)(cc*64 + lane)*4];
            #pragma unroll
            for (int j = 0; j < 4; j++) {
                float4 h0 = *(const float4*)&hL[0][j][cc*4];
                float4 h1 = *(const float4*)&hL[1][j][cc*4];
                float x = a0[j];
                x = fmaf(w4.x, h0.x, x); x = fmaf(w4.y, h0.y, x);
                x = fmaf(w4.z, h0.z, x); x = fmaf(w4.w, h0.w, x);
                a0[j] = x;
                float y = a1[j];
                y = fmaf(w4.x, h1.x, y); y = fmaf(w4.y, h1.y, y);
                y = fmaf(w4.z, h1.z, y); y = fmaf(w4.w, h1.w, y);
                a1[j] = y;
            }
        }
        if (second) {
            #pragma unroll
            for (int j = 0; j < 4; j++) {
                hL[0][j][lane] = lrelu(a0[j] + vb0 + bv);
                hL[1][j][lane] = lrelu(a1[j] + vb1 + bv);
            }
            float s0[4], s1[4];
            #pragma unroll
            for (int j = 0; j < 4; j++) { s0[j] = 0.f; s1[j] = 0.f; }
            #pragma unroll
            for (int cc = 0; cc < 16; cc++) {
                float4 w4 = *(const float4*)&wp[W2Off + (size_t)(cc*64 + lane)*4];
                #pragma unroll
                for (int j = 0; j < 4; j++) {
                    float4 h0 = *(const float4*)&hL[0][j][cc*4];
                    float4 h1 = *(const float4*)&hL[1][j][cc*4];
                    float x = s0[j];
                    x = fmaf(w4.x, h0.x, x); x = fmaf(w4.y, h0.y, x);
                    x = fmaf(w4.z, h0.z, x); x = fmaf(w4.w, h0.w, x);
                    s0[j] = x;
                    float y = s1[j];
                    y = fmaf(w4.x, h1.x, y); y = fmaf(w4.y, h1.y, y);
                    y = fmaf(w4.z, h1.z, y); y = fmaf(w4.w, h1.w, y);
                    s1[j] = y;
                }
            }
            #pragma unroll
            for (int j = 0; j < 4; j++) {
                mx0 = fmaxf(mx0, lrelu(s0[j] + b2v));
                mx1 = fmaxf(mx1, lrelu(s1[j] + b2v));
            }
        } else {
            #pragma unroll
            for (int j = 0; j < 4; j++) {
                mx0 = fmaxf(mx0, lrelu(a0[j] + vb0 + bv));
                mx1 = fmaxf(mx1, lrelu(a1[j] + vb1 + bv));
            }
        }
    }
    xcat[((size_t)b*192 + outCh + lane)*NPT + n0] = mx0;
    xcat[((size_t)b*192 + outCh + lane)*NPT + n1] = mx1;
    xcatTo[((size_t)(b*NPT + n0))*192 + outCh + lane] = mx0;
    xcatTo[((size_t)(b*NPT + n1))*192 + outCh + lane] = mx1;
}

// ---------------- tiled GEMM. OUT: 0=bf16 act (lrelu), 1=gmax partial, 2=final raw (dtype per flag) ----------------
template<int OUT, bool INBF, bool VBIAS>
__global__ __launch_bounds__(256) void gemm_kernel(
        const void* __restrict__ Xv, const float* __restrict__ WT,
        const float* __restrict__ bias, const float* __restrict__ vbias,
        unsigned short* __restrict__ Ybf, float* __restrict__ Yf,
        const int* __restrict__ dflag,
        int Cin, int strideW, int CoutY) {
    __shared__ float wL[16][68];
    __shared__ float xL[16][132];
    __shared__ float gred[64][17];
    int tid = threadIdx.x;
    int tx = tid & 15, ty = tid >> 4;
    int nt = blockIdx.x * 128, ot = blockIdx.y * 64, b = blockIdx.z;
    const float* Xf = (const float*)Xv;
    const unsigned short* Xs = (const unsigned short*)Xv;
    float acc[4][8];
    #pragma unroll
    for (int i = 0; i < 4; i++)
        #pragma unroll
        for (int j = 0; j < 8; j++) acc[i][j] = 0.f;
    for (int c0 = 0; c0 < Cin; c0 += 16) {
        __syncthreads();
        #pragma unroll
        for (int i = 0; i < 4; i++) {
            int idx = tid + i*256; int r = idx >> 6, o = idx & 63;
            wL[r][o] = WT[(size_t)(c0 + r) * strideW + ot + o];
        }
        #pragma unroll
        for (int i = 0; i < 8; i++) {
            int idx = tid + i*256; int r = idx >> 7, m = idx & 127;
            if (INBF) xL[r][m] = bf2f(Xs[(size_t)b * Cin * NPT + (size_t)(c0 + r) * NPT + nt + m]);
            else      xL[r][m] = Xf[(size_t)b * Cin * NPT + (size_t)(c0 + r) * NPT + nt + m];
        }
        __syncthreads();
        #pragma unroll
        for (int kk = 0; kk < 16; kk++) {
            float4 w4 = *(const float4*)&wL[kk][ty*4];
            float4 xa = *(const float4*)&xL[kk][tx*8];
            float4 xb4 = *(const float4*)&xL[kk][tx*8 + 4];
            float wv[4] = {w4.x, w4.y, w4.z, w4.w};
            float xv[8] = {xa.x, xa.y, xa.z, xa.w, xb4.x, xb4.y, xb4.z, xb4.w};
            #pragma unroll
            for (int oi = 0; oi < 4; oi++)
                #pragma unroll
                for (int j = 0; j < 8; j++)
                    acc[oi][j] = fmaf(wv[oi], xv[j], acc[oi][j]);
        }
    }
    if (OUT == 1) {
        #pragma unroll
        for (int oi = 0; oi < 4; oi++) {
            float bb = bias[ot + ty*4 + oi];
            float m = -1e38f;
            #pragma unroll
            for (int j = 0; j < 8; j++) m = fmaxf(m, lrelu(acc[oi][j] + bb));
            gred[ty*4 + oi][tx] = m;
        }
        __syncthreads();
        if (tid < 64) {
            float m = gred[tid][0];
            #pragma unroll
            for (int t = 1; t < 16; t++) m = fmaxf(m, gred[tid][t]);
            Yf[((size_t)b*16 + blockIdx.x)*1024 + ot + tid] = m;
        }
    } else if (OUT == 2) {
        bool f32 = dflag[0] != 0;
        #pragma unroll
        for (int oi = 0; oi < 4; oi++) {
            int o = ot + ty*4 + oi;
            if (o < 50) {
                size_t base = ((size_t)b*50 + o)*NPT + nt + tx*8;
                #pragma unroll
                for (int j = 0; j < 8; j++) {
                    if (f32) Yf[base + j] = acc[oi][j];
                    else     Ybf[base + j] = f2bf(acc[oi][j]);
                }
            }
        }
    } else {
        #pragma unroll
        for (int oi = 0; oi < 4; oi++) {
            int o = ot + ty*4 + oi;
            float bb = bias[o];
            if (VBIAS) bb += vbias[(size_t)b*256 + o];
            size_t base = ((size_t)b*CoutY + o)*NPT + nt + tx*8;
            #pragma unroll
            for (int j = 0; j < 8; j++) Ybf[base + j] = f2bf(lrelu(acc[oi][j] + bb));
        }
    }
}

__global__ __launch_bounds__(256) void gmax_reduce_kernel(const float* __restrict__ gpart, float* __restrict__ g) {
    int o = blockIdx.x * 256 + threadIdx.x;
    int b = blockIdx.y;
    float m = -1e38f;
    for (int ch = 0; ch < 16; ch++) m = fmaxf(m, gpart[((size_t)b*16 + ch)*1024 + o]);
    g[(size_t)b*1024 + o] = m;
}

__global__ __launch_bounds__(256) void v7_part_kernel(const float* __restrict__ wp, const float* __restrict__ g,
                                                      float* __restrict__ v7p) {
    int o = threadIdx.x, ch = blockIdx.x, b = blockIdx.y;
    __shared__ float gL[128];
    if (threadIdx.x < 128) gL[threadIdx.x] = g[(size_t)b*1024 + ch*128 + threadIdx.x];
    __syncthreads();
    float acc = 0.f;
    #pragma unroll 4
    for (int c = 0; c < 128; c++) acc = fmaf(wp[P_W7A + (size_t)(ch*128 + c)*256 + o], gL[c], acc);
    v7p[((size_t)b*8 + ch)*256 + o] = acc;
}

__global__ __launch_bounds__(256) void v7_sum_kernel(const float* __restrict__ v7p, float* __restrict__ v7) {
    int o = threadIdx.x, b = blockIdx.x;
    float acc = 0.f;
    #pragma unroll
    for (int ch = 0; ch < 8; ch++) acc += v7p[((size_t)b*8 + ch)*256 + o];
    v7[(size_t)b*256 + o] = acc;
}

extern "C" void kernel_launch(void* const* d_in, const int* in_sizes, int n_in,
                              void* d_out, int out_size, void* d_ws, size_t ws_size,
                              hipStream_t stream) {
    (void)in_sizes;
    if (n_in < 38 || ws_size < F_TOTAL * sizeof(float)) {
        int nb = (out_size + 255) / 256;
        hipLaunchKernelGGL(zero_out_kernel, dim3(nb), dim3(256), 0, stream,
                           (unsigned short*)d_out, out_size);
        return;
    }
    float* W = (float*)d_ws;
    InPtrs ptrs;
    for (int i = 0; i < 38; i++) ptrs.p[i] = d_in[i];
    int* idx1 = (int*)(W + F_IDX1);
    int* idx2 = (int*)(W + F_IDX2);
    float* wt = W + F_WT;
    float* xcat = W + F_XCAT;
    float* xcatT = W + F_XCATT;
    unsigned short* x7 = (unsigned short*)(W + F_X7);
    unsigned short* x8 = (unsigned short*)(W + F_X8);
    unsigned short* x9 = (unsigned short*)(W + F_X9);
    float* gpart = W + F_GPART;
    float* g = W + F_G;
    float* v7p = W + F_V7P;
    float* v7 = W + F_V7;
    float* wp = W + F_WP;
    int* dflag = (int*)(W + F_FLAG);
    float* xxg = W + F_XX;

    hipLaunchKernelGGL(detect_kernel, dim3(1), dim3(256), 0, stream,
                       (const unsigned short*)d_in[0], dflag);
    hipLaunchKernelGGL(prep_kernel, dim3(256), dim3(256), 0, stream, ptrs, wp, dflag);
    hipLaunchKernelGGL(knn_xyz_kernel, dim3(4096), dim3(256), 0, stream, d_in[0], dflag, idx1, wt);
    hipLaunchKernelGGL(stage1_kernel, dim3(16384), dim3(64), 0, stream, d_in[0], dflag, idx1, wt, wp, xcat, xcatT);
    hipLaunchKernelGGL(norms_kernel, dim3(32), dim3(512), 0, stream, xcat, 0, xxg);
    hipLaunchKernelGGL(knn_feat_kernel, dim3(2048), dim3(512), 0, stream, xcat, xcatT, xxg, 0, idx2);
    hipLaunchKernelGGL(stage23_kernel, dim3(8192), dim3(64), 0, stream, xcatT, idx2, wt, wp,
        (int)P_AMP2, (int)P_BMP2, (int)P_W3A, (int)P_W3B, (int)P_B3, (int)P_W4, (int)P_B4,
        0, 64, 1, xcat, xcatT);
    hipLaunchKernelGGL(norms_kernel, dim3(32), dim3(512), 0, stream, xcat, 64, xxg);
    hipLaunchKernelGGL(knn_feat_kernel, dim3(2048), dim3(512), 0, stream, xcat, xcatT, xxg, 64, idx2);
    hipLaunchKernelGGL(stage23_kernel, dim3(8192), dim3(64), 0, stream, xcatT, idx2, wt, wp,
        (int)P_AMP3, (int)P_BMP3, (int)P_W5A, (int)P_W5B, (int)P_B5, 0, 0,
        64, 128, 0, xcat, xcatT);
    hipLaunchKernelGGL((gemm_kernel<1,false,false>), dim3(16,16,8), dim3(256), 0, stream,
        (const void*)xcat, wp + P_W6, wp + P_B6, (const float*)nullptr,
        (unsigned short*)nullptr, gpart, dflag, 192, 1024, 1024);
    hipLaunchKernelGGL(gmax_reduce_kernel, dim3(4,8), dim3(256), 0, stream, gpart, g);
    hipLaunchKernelGGL(v7_part_kernel, dim3(8,8), dim3(256), 0, stream, wp, g, v7p);
    hipLaunchKernelGGL(v7_sum_kernel, dim3(8), dim3(256), 0, stream, v7p, v7);
    hipLaunchKernelGGL((gemm_kernel<0,false,true>), dim3(16,4,8), dim3(256), 0, stream,
        (const void*)xcat, wp + P_W7B, wp + P_B7, v7, x7, (float*)nullptr, dflag, 192, 256, 256);
    hipLaunchKernelGGL((gemm_kernel<0,true,false>), dim3(16,4,8), dim3(256), 0, stream,
        (const void*)x7, wp + P_W8, wp + P_B8, (const float*)nullptr, x8, (float*)nullptr, dflag, 256, 256, 256);
    hipLaunchKernelGGL((gemm_kernel<0,true,false>), dim3(16,2,8), dim3(256), 0, stream,
        (const void*)x8, wp + P_W9, wp + P_B9, (const float*)nullptr, x9, (float*)nullptr, dflag, 256, 128, 128);
    hipLaunchKernelGGL((gemm_kernel<2,true,false>), dim3(16,1,8), dim3(256), 0, stream,
        (const void*)x9, wp + P_W10, (const float*)nullptr, (const float*)nullptr,
        (unsigned short*)d_out, (float*)d_out, dflag, 128, 64, 50);
}

// Round 13
// 1482.916 us; speedup vs baseline: 1.0712x; 1.0712x over previous
//
#include <hip/hip_runtime.h>
#include <hip/hip_bf16.h>

#define NPT 2048
#define NB 8
#define KNN 20

__device__ __forceinline__ float bf2f(unsigned short u) {
    return __uint_as_float(((unsigned)u) << 16);
}
__device__ __forceinline__ unsigned short f2bf(float f) {
    unsigned u = __float_as_uint(f);
    unsigned lsb = (u >> 16) & 1u;
    u += 0x7fffu + lsb;
    return (unsigned short)(u >> 16);
}
__device__ __forceinline__ float lrelu(float x) { return x >= 0.f ? x : 0.2f * x; }
__device__ __forceinline__ float ldin(const void* p, size_t i, bool f32) {
    return f32 ? ((const float*)p)[i] : bf2f(((const unsigned short*)p)[i]);
}
__device__ __forceinline__ float rfl(float x) {
    return __int_as_float(__builtin_amdgcn_readfirstlane(__float_as_int(x)));
}
// 64-bit sortable key: FULL ordered-fp32 distance in bits [42:11], low 11 bits
// = 2047-m (tie -> lower index). Unique keys; strict-descending selection
// reproduces jax top_k (value desc, index asc) exactly. 0 = empty sentinel.
__device__ __forceinline__ unsigned long long mkkey64(float d, int m) {
    unsigned u = __float_as_uint(d);
    unsigned p = u ^ (unsigned)(((int)u >> 31) | 0x80000000);
    return ((unsigned long long)p << 11) | (unsigned)(2047 - m);
}
__device__ __forceinline__ unsigned long long shfl_xor_u64(unsigned long long v, int off) {
    unsigned lo = (unsigned)__shfl_xor((int)(unsigned)(v & 0xFFFFFFFFull), off);
    unsigned hi = (unsigned)__shfl_xor((int)(unsigned)(v >> 32), off);
    return ((unsigned long long)hi << 32) | lo;
}

// Top-KNN selection over 32 distances/lane (key recomputed on the fly from
// slot geometry m = (s>>SH)*STR + lane*LM + (s&MK)); per-lane top-2 buffer.
template<int SH, int STR, int LM, int MK>
__device__ __forceinline__ void select_topk_d(const float* __restrict__ d, int lane, int* mymp) {
    unsigned long long b1 = 0ull, b2 = 0ull;
    #pragma unroll
    for (int s = 0; s < 32; s++) {
        int m = (s >> SH)*STR + lane*LM + (s & MK);
        unsigned long long v = mkkey64(d[s], m);
        bool gt1 = v > b1;
        unsigned long long nb2 = gt1 ? b1 : (v > b2 ? v : b2);
        b1 = gt1 ? v : b1;
        b2 = nb2;
    }
    unsigned long long lastpop = ~0ull;
    int mym = 0;
    #pragma unroll 1
    for (int k = 0; k < KNN; k++) {
        unsigned long long best = b1;
        #pragma unroll
        for (int off = 32; off > 0; off >>= 1) {
            unsigned long long o = shfl_xor_u64(best, off);
            best = o > best ? o : best;
        }
        if (lane == k) mym = 2047 - (int)(best & 2047ull);
        bool won = (b1 == best) && (best != 0ull);
        if (won) { lastpop = b1; b1 = b2; b2 = 0ull; }
        bool dirty = won && (b1 == 0ull);
        if (__ballot(dirty)) {
            if (dirty) {
                unsigned long long n1 = 0ull, n2 = 0ull;
                #pragma unroll
                for (int s = 0; s < 32; s++) {
                    int m = (s >> SH)*STR + lane*LM + (s & MK);
                    unsigned long long v = mkkey64(d[s], m);
                    v = (v < lastpop) ? v : 0ull;
                    bool gt1 = v > n1;
                    unsigned long long t2 = gt1 ? n1 : (v > n2 ? v : n2);
                    n1 = gt1 ? v : n1;
                    n2 = t2;
                }
                b1 = n1; b2 = n2;
            }
        }
    }
    *mymp = mym;
}

// ---------------- workspace layout (float units), liveness-overlapped ----------------
constexpr size_t F_IDX1  = 0;
constexpr size_t F_IDX2  = 327680;
constexpr size_t F_WT    = 655360;
constexpr size_t F_XCATT = 983040;     // (B,N,192) -> 4128768
constexpr size_t F_XCAT  = 4128768;    // (B,192,N) -> 7274496
constexpr size_t F_GPART = 7274496;
constexpr size_t F_G     = 7405568;
constexpr size_t F_V7P   = 7413760;
constexpr size_t F_V7    = 7430144;
constexpr size_t F_WP    = 7432192;    // -> 8074048
constexpr size_t F_FLAG  = 8074048;
constexpr size_t F_XX    = 8074052;    // (B,2048) column norms -> 8090436
constexpr size_t F_X7    = 0;          // bf16 (B,256,N) over dead idx/wt/xcatT-head
constexpr size_t F_X8    = 2097152;    // bf16 (B,256,N)
constexpr size_t F_X9    = 4194304;    // bf16 (B,128,N) over dead xcat
constexpr size_t F_TOTAL = 8090436;

constexpr size_t P_AMP1 = 0;
constexpr size_t P_BMP1 = 64;
constexpr size_t P_AMP2 = 128;
constexpr size_t P_BMP2 = 192;
constexpr size_t P_AMP3 = 256;
constexpr size_t P_BMP3 = 320;
constexpr size_t P_W1   = 384;
constexpr size_t P_B1   = 896;
constexpr size_t P_W2   = 960;
constexpr size_t P_B2   = 5056;
constexpr size_t P_W3A  = 5120;
constexpr size_t P_W3B  = 9216;
constexpr size_t P_B3   = 13312;
constexpr size_t P_W4   = 13376;
constexpr size_t P_B4   = 17472;
constexpr size_t P_W5A  = 17536;
constexpr size_t P_W5B  = 21632;
constexpr size_t P_B5   = 25728;
constexpr size_t P_W6   = 25792;
constexpr size_t P_B6   = 222400;
constexpr size_t P_W7A  = 223424;
constexpr size_t P_W7B  = 485568;
constexpr size_t P_B7   = 534720;
constexpr size_t P_W8   = 534976;
constexpr size_t P_B8   = 600512;
constexpr size_t P_W9   = 600768;
constexpr size_t P_B9   = 633536;
constexpr size_t P_W10  = 633664;

struct InPtrs { const void* p[38]; };

__global__ __launch_bounds__(256) void zero_out_kernel(unsigned short* out, int nelem) {
    int i = blockIdx.x * 256 + threadIdx.x;
    if (i < nelem) out[i] = 0;
}

// ---------------- dtype detection (even ushorts: fp32 low-mantissa halves) ----------------
__global__ __launch_bounds__(256) void detect_kernel(const unsigned short* __restrict__ u,
                                                     int* __restrict__ flag) {
    __shared__ int red[256];
    int tid = threadIdx.x;
    int cnt = 0;
    for (int i = tid * 2; i < 98304; i += 512) {
        unsigned e = (u[i] >> 7) & 0xFFu;
        cnt += (e == 0xFFu) ? 1 : 0;
    }
    red[tid] = cnt;
    __syncthreads();
    for (int s = 128; s > 0; s >>= 1) {
        if (tid < s) red[tid] += red[tid + s];
        __syncthreads();
    }
    if (tid == 0) flag[0] = (red[0] > 8) ? 1 : 0;
}

// ---------------- weight prep ----------------
__global__ __launch_bounds__(256) void prep_kernel(InPtrs in, float* __restrict__ wp,
                                                   const int* __restrict__ dflag) {
    bool f32 = dflag[0] != 0;
    int gtid = blockIdx.x * 256 + threadIdx.x;
    int gstr = gridDim.x * 256;
    if (gtid < 192) {
        int which = gtid >> 6, o = gtid & 63;
        const void *w, *s, *bb; int cin, cout; size_t ao, bo;
        if (which == 0)      { w = in.p[1]; s = in.p[2]; bb = in.p[3]; cin = 3;  cout = 3;  ao = P_AMP1; bo = P_BMP1; }
        else if (which == 1) { w = in.p[4]; s = in.p[5]; bb = in.p[6]; cin = 64; cout = 64; ao = P_AMP2; bo = P_BMP2; }
        else                 { w = in.p[7]; s = in.p[8]; bb = in.p[9]; cin = 64; cout = 64; ao = P_AMP3; bo = P_BMP3; }
        if (o < cout) {
            float sum = 0.f;
            for (int c = 0; c < cin; c++) sum += ldin(w, o*cin + c, f32);
            wp[ao + o] = sum * ldin(s, o, f32);
            wp[bo + o] = ldin(bb, o, f32);
        }
    }
    for (int i = gtid; i < 512; i += gstr) {
        int q = i & 3, o = (i >> 2) & 63, cc = i >> 8, c = cc*4 + q;
        wp[P_W1 + i] = (c < 6) ? ldin(in.p[10], o*6 + c, f32) * ldin(in.p[11], o, f32) : 0.f;
    }
    for (int i = gtid; i < 64; i += gstr) wp[P_B1 + i] = ldin(in.p[12], i, f32);
    for (int i = gtid; i < 4096; i += gstr) {
        int q = i & 3, o = (i >> 2) & 63, cc = i >> 8;
        wp[P_W2 + i] = ldin(in.p[13], o*64 + cc*4 + q, f32) * ldin(in.p[14], o, f32);
    }
    for (int i = gtid; i < 64; i += gstr) wp[P_B2 + i] = ldin(in.p[15], i, f32);
    for (int i = gtid; i < 4096; i += gstr) {
        int q = i & 3, o = (i >> 2) & 63, cc = i >> 8;
        float sc = ldin(in.p[17], o, f32);
        wp[P_W3A + i] = ldin(in.p[16], o*128 + cc*4 + q, f32) * sc;
        wp[P_W3B + i] = ldin(in.p[16], o*128 + 64 + cc*4 + q, f32) * sc;
    }
    for (int i = gtid; i < 64; i += gstr) wp[P_B3 + i] = ldin(in.p[18], i, f32);
    for (int i = gtid; i < 4096; i += gstr) {
        int q = i & 3, o = (i >> 2) & 63, cc = i >> 8;
        wp[P_W4 + i] = ldin(in.p[19], o*64 + cc*4 + q, f32) * ldin(in.p[20], o, f32);
    }
    for (int i = gtid; i < 64; i += gstr) wp[P_B4 + i] = ldin(in.p[21], i, f32);
    for (int i = gtid; i < 4096; i += gstr) {
        int q = i & 3, o = (i >> 2) & 63, cc = i >> 8;
        float sc = ldin(in.p[23], o, f32);
        wp[P_W5A + i] = ldin(in.p[22], o*128 + cc*4 + q, f32) * sc;
        wp[P_W5B + i] = ldin(in.p[22], o*128 + 64 + cc*4 + q, f32) * sc;
    }
    for (int i = gtid; i < 64; i += gstr) wp[P_B5 + i] = ldin(in.p[24], i, f32);
    for (int i = gtid; i < 192*1024; i += gstr) {
        int o = i & 1023, c = i >> 10;
        wp[P_W6 + i] = ldin(in.p[25], o*192 + c, f32) * ldin(in.p[26], o, f32);
    }
    for (int i = gtid; i < 1024; i += gstr) wp[P_B6 + i] = ldin(in.p[27], i, f32);
    for (int i = gtid; i < 1024*256; i += gstr) {
        int o = i & 255, c = i >> 8;
        wp[P_W7A + i] = ldin(in.p[28], o*1216 + c, f32) * ldin(in.p[29], o, f32);
    }
    for (int i = gtid; i < 192*256; i += gstr) {
        int o = i & 255, c = i >> 8;
        wp[P_W7B + i] = ldin(in.p[28], o*1216 + 1024 + c, f32) * ldin(in.p[29], o, f32);
    }
    for (int i = gtid; i < 256; i += gstr) wp[P_B7 + i] = ldin(in.p[30], i, f32);
    for (int i = gtid; i < 256*256; i += gstr) {
        int o = i & 255, c = i >> 8;
        wp[P_W8 + i] = ldin(in.p[31], o*256 + c, f32) * ldin(in.p[32], o, f32);
    }
    for (int i = gtid; i < 256; i += gstr) wp[P_B8 + i] = ldin(in.p[33], i, f32);
    for (int i = gtid; i < 256*128; i += gstr) {
        int o = i & 127, c = i >> 7;
        wp[P_W9 + i] = ldin(in.p[34], o*256 + c, f32) * ldin(in.p[35], o, f32);
    }
    for (int i = gtid; i < 128; i += gstr) wp[P_B9 + i] = ldin(in.p[36], i, f32);
    for (int i = gtid; i < 128*64; i += gstr) {
        int o = i & 63, c = i >> 6;
        wp[P_W10 + i] = (o < 50) ? ldin(in.p[37], o*128 + c, f32) : 0.f;
    }
}

// ---------------- xyz KNN + manifold weight ----------------
__global__ __launch_bounds__(256) void knn_xyz_kernel(const void* __restrict__ xin,
                                                      const int* __restrict__ dflag,
                                                      int* __restrict__ idx_out,
                                                      float* __restrict__ wt_out) {
    bool f32 = dflag[0] != 0;
    int lane = threadIdx.x & 63, wid = threadIdx.x >> 6;
    int p = blockIdx.x * 4 + wid;
    int b = p >> 11, n = p & 2047;
    size_t eb = (size_t)b * 6 * NPT;
    float cx0 = ldin(xin, eb + n, f32), cx1 = ldin(xin, eb + NPT + n, f32), cx2 = ldin(xin, eb + 2*NPT + n, f32);
    float xxn = __builtin_fmaf(cx2, cx2, __builtin_fmaf(cx1, cx1, cx0*cx0));
    float d[32];
    #pragma unroll
    for (int j4 = 0; j4 < 8; j4++) {
        int m0 = j4*256 + lane*4;
        float x0q[4], x1q[4], x2q[4];
        if (f32) {
            const float* xf = (const float*)xin + eb;
            float4 a0 = *(const float4*)(xf + m0);
            float4 a1 = *(const float4*)(xf + NPT + m0);
            float4 a2 = *(const float4*)(xf + 2*NPT + m0);
            x0q[0]=a0.x; x0q[1]=a0.y; x0q[2]=a0.z; x0q[3]=a0.w;
            x1q[0]=a1.x; x1q[1]=a1.y; x1q[2]=a1.z; x1q[3]=a1.w;
            x2q[0]=a2.x; x2q[1]=a2.y; x2q[2]=a2.z; x2q[3]=a2.w;
        } else {
            const unsigned short* xu = (const unsigned short*)xin + eb;
            ushort4 a0 = *(const ushort4*)(xu + m0);
            ushort4 a1 = *(const ushort4*)(xu + NPT + m0);
            ushort4 a2 = *(const ushort4*)(xu + 2*NPT + m0);
            x0q[0]=bf2f(a0.x); x0q[1]=bf2f(a0.y); x0q[2]=bf2f(a0.z); x0q[3]=bf2f(a0.w);
            x1q[0]=bf2f(a1.x); x1q[1]=bf2f(a1.y); x1q[2]=bf2f(a1.z); x1q[3]=bf2f(a1.w);
            x2q[0]=bf2f(a2.x); x2q[1]=bf2f(a2.y); x2q[2]=bf2f(a2.z); x2q[3]=bf2f(a2.w);
        }
        #pragma unroll
        for (int q = 0; q < 4; q++) {
            float x0 = x0q[q], x1 = x1q[q], x2 = x2q[q];
            float inner = __builtin_fmaf(x2, cx2, __builtin_fmaf(x1, cx1, x0*cx0));
            float xxm   = __builtin_fmaf(x2, x2,  __builtin_fmaf(x1, x1,  x0*x0));
            d[j4*4 + q] = __builtin_fmaf(2.f, inner, -xxn) - xxm;
        }
    }
    int mym;
    select_topk_d<2,256,4,3>(d, lane, &mym);
    if (lane < KNN) idx_out[(size_t)p*KNN + lane] = mym;
    int m0n = __shfl(mym, 0);
    if (lane < KNN) {
        size_t nb0 = eb + 3*NPT;
        float c0 = ldin(xin, nb0 + m0n, f32), c1 = ldin(xin, nb0 + NPT + m0n, f32), c2 = ldin(xin, nb0 + 2*NPT + m0n, f32);
        float g0 = ldin(xin, nb0 + mym, f32), g1 = ldin(xin, nb0 + NPT + mym, f32), g2 = ldin(xin, nb0 + 2*NPT + mym, f32);
        float cn = sqrtf(__builtin_fmaf(c2, c2, __builtin_fmaf(c1, c1, c0*c0)));
        float gn = sqrtf(__builtin_fmaf(g2, g2, __builtin_fmaf(g1, g1, g0*g0)));
        float num = __builtin_fmaf(c2, g2, __builtin_fmaf(c1, g1, c0*g0));
        wt_out[(size_t)p*KNN + lane] = num / fmaxf(cn * gn, 1e-8f);
    }
}

// ---------------- column norms for feature KNN ----------------
__global__ __launch_bounds__(512) void norms_kernel(const float* __restrict__ xcat, int inRow,
                                                    float* __restrict__ xxg) {
    int t = blockIdx.x * 512 + threadIdx.x;   // 16384
    int b = t >> 11, m = t & 2047;
    const float* xb = xcat + ((size_t)b*192 + inRow) * NPT + m;
    float s = 0.f;
    #pragma unroll
    for (int c = 0; c < 64; c++) { float v = xb[(size_t)c*NPT]; s = __builtin_fmaf(v, v, s); }
    xxg[t] = s;
}

// ---------------- feature-space KNN (C=64): 1 query/wave, 256-m chunks, b128 LDS reads ----------------
__global__ __launch_bounds__(512) void knn_feat_kernel(const float* __restrict__ xcat,
        const float* __restrict__ xcatT, const float* __restrict__ xxg,
        int inOff, int* __restrict__ idx_out) {
    __shared__ float xmL[64][256];   // 64 KB (per-WG LDS limit)
    int tid = threadIdx.x, lane = tid & 63, wid = tid >> 6;
    int p = blockIdx.x * 8 + wid;
    int b = p >> 11, n = p & 2047;
    const float* xb = xcat + ((size_t)b*192 + inOff) * NPT;
    const float* qg = xcatT + ((size_t)(b*NPT + n))*192 + inOff;
    float q[64];
    #pragma unroll
    for (int c4 = 0; c4 < 16; c4++) {
        float4 v = *(const float4*)(qg + c4*4);
        q[c4*4+0] = rfl(v.x); q[c4*4+1] = rfl(v.y);
        q[c4*4+2] = rfl(v.z); q[c4*4+3] = rfl(v.w);
    }
    float xxn = xxg[b*2048 + n];
    float d[32];
    #pragma unroll
    for (int ch = 0; ch < 8; ch++) {
        __syncthreads();
        #pragma unroll
        for (int i = 0; i < 8; i++) {
            int idx4 = tid + i*512;
            int c = idx4 >> 6, m4 = (idx4 & 63) * 4;
            *(float4*)&xmL[c][m4] = *(const float4*)(xb + (size_t)c*NPT + ch*256 + m4);
        }
        __syncthreads();
        float in0 = 0.f, in1 = 0.f, in2 = 0.f, in3 = 0.f;
        #pragma unroll
        for (int c = 0; c < 64; c++) {
            float4 v = *(const float4*)&xmL[c][4*lane];
            in0 = __builtin_fmaf(q[c], v.x, in0);
            in1 = __builtin_fmaf(q[c], v.y, in1);
            in2 = __builtin_fmaf(q[c], v.z, in2);
            in3 = __builtin_fmaf(q[c], v.w, in3);
        }
        float4 xxv = *(const float4*)&xxg[b*2048 + ch*256 + 4*lane];
        d[ch*4+0] = __builtin_fmaf(2.f, in0, -xxn) - xxv.x;
        d[ch*4+1] = __builtin_fmaf(2.f, in1, -xxn) - xxv.y;
        d[ch*4+2] = __builtin_fmaf(2.f, in2, -xxn) - xxv.z;
        d[ch*4+3] = __builtin_fmaf(2.f, in3, -xxn) - xxv.w;
    }
    int mym;
    select_topk_d<2,256,4,3>(d, lane, &mym);
    if (lane < KNN) idx_out[(size_t)p*KNN + lane] = mym;
}

// ---------------- stage 1 (xyz edge conv -> x1), 1 wave/block, barrier-free ----------------
__global__ __launch_bounds__(64) void stage1_kernel(const void* __restrict__ xin,
        const int* __restrict__ dflag,
        const int* __restrict__ idxb, const float* __restrict__ wtb,
        const float* __restrict__ wp, float* __restrict__ xcat, float* __restrict__ xcatT) {
    __shared__ float y1L[KNN][64];
    bool f32 = dflag[0] != 0;
    int lane = threadIdx.x & 63;
    int p = blockIdx.x, b = p >> 11, n = p & 2047;
    size_t eb = (size_t)b * 6 * NPT;
    int myidx = 0; float mywt = 0.f;
    if (lane < KNN) {
        myidx = idxb[(size_t)p*KNN + lane] & 2047;
        mywt  = wtb[(size_t)p*KNN + lane];
    }
    float cx0 = ldin(xin, eb + n, f32), cx1 = ldin(xin, eb + NPT + n, f32), cx2 = ldin(xin, eb + 2*NPT + n, f32);
    float aM0 = wp[P_AMP1+0], aM1 = wp[P_AMP1+1], aM2 = wp[P_AMP1+2];
    float bM0 = wp[P_BMP1+0], bM1 = wp[P_BMP1+1], bM2 = wp[P_BMP1+2];
    float w1r[8];
    #pragma unroll
    for (int cc = 0; cc < 2; cc++) {
        float4 v = *(const float4*)&wp[P_W1 + (size_t)(cc*64 + lane)*4];
        w1r[cc*4+0] = v.x; w1r[cc*4+1] = v.y; w1r[cc*4+2] = v.z; w1r[cc*4+3] = v.w;
    }
    float b1v = wp[P_B1 + lane];
    #pragma unroll
    for (int k = 0; k < KNN; k++) {
        int m = __shfl(myidx, k);
        float w = __shfl(mywt, k);
        float n0 = ldin(xin, eb + m, f32), n1 = ldin(xin, eb + NPT + m, f32), n2 = ldin(xin, eb + 2*NPT + m, f32);
        float h0 = (n0 - cx0) * lrelu(fmaf(aM0, w, bM0));
        float h1 = (n1 - cx1) * lrelu(fmaf(aM1, w, bM1));
        float h2 = (n2 - cx2) * lrelu(fmaf(aM2, w, bM2));
        float acc = w1r[0]*h0 + w1r[1]*h1 + w1r[2]*h2 + w1r[3]*cx0 + w1r[4]*cx1 + w1r[5]*cx2;
        y1L[k][lane] = lrelu(acc + b1v);
    }
    float acc2[KNN];
    #pragma unroll
    for (int k = 0; k < KNN; k++) acc2[k] = 0.f;
    #pragma unroll
    for (int cc = 0; cc < 16; cc++) {
        float4 w4 = *(const float4*)&wp[P_W2 + (size_t)(cc*64 + lane)*4];
        #pragma unroll
        for (int k = 0; k < KNN; k++) {
            float4 h4 = *(const float4*)&y1L[k][cc*4];
            float a = acc2[k];
            a = fmaf(w4.x, h4.x, a); a = fmaf(w4.y, h4.y, a);
            a = fmaf(w4.z, h4.z, a); a = fmaf(w4.w, h4.w, a);
            acc2[k] = a;
        }
    }
    float b2v = wp[P_B2 + lane];
    float mx = -1e38f;
    #pragma unroll
    for (int k = 0; k < KNN; k++) mx = fmaxf(mx, lrelu(acc2[k] + b2v));
    xcat[((size_t)b*192 + lane)*NPT + n] = mx;
    xcatT[((size_t)(b*NPT + n))*192 + lane] = mx;
}

// ---------------- stages 2/3 (feature edge conv), 1 wave/block, barrier-free ----------------
__global__ __launch_bounds__(64) void stage23_kernel(
        const float* __restrict__ xcatT, const int* __restrict__ idxb, const float* __restrict__ wtb,
        const float* __restrict__ wp,
        int aOff, int bmpOff, int WaOff, int WbOff, int biasOff,
        int W2Off, int bias2Off, int inOff, int outCh, int second,
        float* __restrict__ xcat, float* __restrict__ xcatTo) {
    __shared__ float hL[KNN][64];
    __shared__ float cL[64];
    int lane = threadIdx.x & 63;
    int p = blockIdx.x, b = p >> 11, n = p & 2047;
    const float* xTb = xcatT + (size_t)b * NPT * 192 + inOff;
    int myidx = 0; float mywt = 0.f;
    if (lane < KNN) {
        myidx = idxb[(size_t)p*KNN + lane] & 2047;
        mywt  = wtb[(size_t)p*KNN + lane];
    }
    float cv = xTb[(size_t)n * 192 + lane];
    cL[lane] = cv;
    float aMP = wp[aOff + lane], bMP = wp[bmpOff + lane];
    #pragma unroll
    for (int k = 0; k < KNN; k++) {
        int m = __shfl(myidx, k);
        float w = __shfl(mywt, k);
        float nb = xTb[(size_t)m * 192 + lane];
        hL[k][lane] = (nb - cv) * lrelu(fmaf(aMP, w, bMP));
    }
    float vb = 0.f;
    #pragma unroll
    for (int cc = 0; cc < 16; cc++) {
        float4 w4 = *(const float4*)&wp[WbOff + (size_t)(cc*64 + lane)*4];
        float4 c4 = *(const float4*)&cL[cc*4];
        vb = fmaf(w4.x, c4.x, vb); vb = fmaf(w4.y, c4.y, vb);
        vb = fmaf(w4.z, c4.z, vb); vb = fmaf(w4.w, c4.w, vb);
    }
    float acc[KNN];
    #pragma unroll
    for (int k = 0; k < KNN; k++) acc[k] = 0.f;
    #pragma unroll
    for (int cc = 0; cc < 16; cc++) {
        float4 w4 = *(const float4*)&wp[WaOff + (size_t)(cc*64 + lane)*4];
        #pragma unroll
        for (int k = 0; k < KNN; k++) {
            float4 h4 = *(const float4*)&hL[k][cc*4];
            float a = acc[k];
            a = fmaf(w4.x, h4.x, a); a = fmaf(w4.y, h4.y, a);
            a = fmaf(w4.z, h4.z, a); a = fmaf(w4.w, h4.w, a);
            acc[k] = a;
        }
    }
    float bv = wp[biasOff + lane];
    float mx = -1e38f;
    if (second) {
        #pragma unroll
        for (int k = 0; k < KNN; k++) hL[k][lane] = lrelu(acc[k] + vb + bv);
        float acc2[KNN];
        #pragma unroll
        for (int k = 0; k < KNN; k++) acc2[k] = 0.f;
        #pragma unroll
        for (int cc = 0; cc < 16; cc++) {
            float4 w4 = *(const float4*)&wp[W2Off + (size_t)(cc*64 + lane)*4];
            #pragma unroll
            for (int k = 0; k < KNN; k++) {
                float4 h4 = *(const float4*)&hL[k][cc*4];
                float a = acc2[k];
                a = fmaf(w4.x, h4.x, a); a = fmaf(w4.y, h4.y, a);
                a = fmaf(w4.z, h4.z, a); a = fmaf(w4.w, h4.w, a);
                acc2[k] = a;
            }
        }
        float b2v = wp[bias2Off + lane];
        #pragma unroll
        for (int k = 0; k < KNN; k++) mx = fmaxf(mx, lrelu(acc2[k] + b2v));
    } else {
        #pragma unroll
        for (int k = 0; k < KNN; k++) mx = fmaxf(mx, lrelu(acc[k] + vb + bv));
    }
    xcat[((size_t)b*192 + outCh + lane)*NPT + n] = mx;
    xcatTo[((size_t)(b*NPT + n))*192 + outCh + lane] = mx;
}

// ---------------- tiled GEMM. OUT: 0=bf16 act (lrelu), 1=gmax partial, 2=final raw (dtype per flag) ----------------
template<int OUT, bool INBF, bool VBIAS>
__global__ __launch_bounds__(256) void gemm_kernel(
        const void* __restrict__ Xv, const float* __restrict__ WT,
        const float* __restrict__ bias, const float* __restrict__ vbias,
        unsigned short* __restrict__ Ybf, float* __restrict__ Yf,
        const int* __restrict__ dflag,
        int Cin, int strideW, int CoutY) {
    __shared__ float wL[16][68];
    __shared__ float xL[16][132];
    __shared__ float gred[64][17];
    int tid = threadIdx.x;
    int tx = tid & 15, ty = tid >> 4;
    int nt = blockIdx.x * 128, ot = blockIdx.y * 64, b = blockIdx.z;
    const float* Xf = (const float*)Xv;
    const unsigned short* Xs = (const unsigned short*)Xv;
    float acc[4][8];
    #pragma unroll
    for (int i = 0; i < 4; i++)
        #pragma unroll
        for (int j = 0; j < 8; j++) acc[i][j] = 0.f;
    for (int c0 = 0; c0 < Cin; c0 += 16) {
        __syncthreads();
        #pragma unroll
        for (int i = 0; i < 4; i++) {
            int idx = tid + i*256; int r = idx >> 6, o = idx & 63;
            wL[r][o] = WT[(size_t)(c0 + r) * strideW + ot + o];
        }
        #pragma unroll
        for (int i = 0; i < 8; i++) {
            int idx = tid + i*256; int r = idx >> 7, m = idx & 127;
            if (INBF) xL[r][m] = bf2f(Xs[(size_t)b * Cin * NPT + (size_t)(c0 + r) * NPT + nt + m]);
            else      xL[r][m] = Xf[(size_t)b * Cin * NPT + (size_t)(c0 + r) * NPT + nt + m];
        }
        __syncthreads();
        #pragma unroll
        for (int kk = 0; kk < 16; kk++) {
            float4 w4 = *(const float4*)&wL[kk][ty*4];
            float4 xa = *(const float4*)&xL[kk][tx*8];
            float4 xb4 = *(const float4*)&xL[kk][tx*8 + 4];
            float wv[4] = {w4.x, w4.y, w4.z, w4.w};
            float xv[8] = {xa.x, xa.y, xa.z, xa.w, xb4.x, xb4.y, xb4.z, xb4.w};
            #pragma unroll
            for (int oi = 0; oi < 4; oi++)
                #pragma unroll
                for (int j = 0; j < 8; j++)
                    acc[oi][j] = fmaf(wv[oi], xv[j], acc[oi][j]);
        }
    }
    if (OUT == 1) {
        #pragma unroll
        for (int oi = 0; oi < 4; oi++) {
            float bb = bias[ot + ty*4 + oi];
            float m = -1e38f;
            #pragma unroll
            for (int j = 0; j < 8; j++) m = fmaxf(m, lrelu(acc[oi][j] + bb));
            gred[ty*4 + oi][tx] = m;
        }
        __syncthreads();
        if (tid < 64) {
            float m = gred[tid][0];
            #pragma unroll
            for (int t = 1; t < 16; t++) m = fmaxf(m, gred[tid][t]);
            Yf[((size_t)b*16 + blockIdx.x)*1024 + ot + tid] = m;
        }
    } else if (OUT == 2) {
        bool f32 = dflag[0] != 0;
        #pragma unroll
        for (int oi = 0; oi < 4; oi++) {
            int o = ot + ty*4 + oi;
            if (o < 50) {
                size_t base = ((size_t)b*50 + o)*NPT + nt + tx*8;
                #pragma unroll
                for (int j = 0; j < 8; j++) {
                    if (f32) Yf[base + j] = acc[oi][j];
                    else     Ybf[base + j] = f2bf(acc[oi][j]);
                }
            }
        }
    } else {
        #pragma unroll
        for (int oi = 0; oi < 4; oi++) {
            int o = ot + ty*4 + oi;
            float bb = bias[o];
            if (VBIAS) bb += vbias[(size_t)b*256 + o];
            size_t base = ((size_t)b*CoutY + o)*NPT + nt + tx*8;
            #pragma unroll
            for (int j = 0; j < 8; j++) Ybf[base + j] = f2bf(lrelu(acc[oi][j] + bb));
        }
    }
}

__global__ __launch_bounds__(256) void gmax_reduce_kernel(const float* __restrict__ gpart, float* __restrict__ g) {
    int o = blockIdx.x * 256 + threadIdx.x;
    int b = blockIdx.y;
    float m = -1e38f;
    for (int ch = 0; ch < 16; ch++) m = fmaxf(m, gpart[((size_t)b*16 + ch)*1024 + o]);
    g[(size_t)b*1024 + o] = m;
}

__global__ __launch_bounds__(256) void v7_part_kernel(const float* __restrict__ wp, const float* __restrict__ g,
                                                      float* __restrict__ v7p) {
    int o = threadIdx.x, ch = blockIdx.x, b = blockIdx.y;
    __shared__ float gL[128];
    if (threadIdx.x < 128) gL[threadIdx.x] = g[(size_t)b*1024 + ch*128 + threadIdx.x];
    __syncthreads();
    float acc = 0.f;
    #pragma unroll 4
    for (int c = 0; c < 128; c++) acc = fmaf(wp[P_W7A + (size_t)(ch*128 + c)*256 + o], gL[c], acc);
    v7p[((size_t)b*8 + ch)*256 + o] = acc;
}

__global__ __launch_bounds__(256) void v7_sum_kernel(const float* __restrict__ v7p, float* __restrict__ v7) {
    int o = threadIdx.x, b = blockIdx.x;
    float acc = 0.f;
    #pragma unroll
    for (int ch = 0; ch < 8; ch++) acc += v7p[((size_t)b*8 + ch)*256 + o];
    v7[(size_t)b*256 + o] = acc;
}

extern "C" void kernel_launch(void* const* d_in, const int* in_sizes, int n_in,
                              void* d_out, int out_size, void* d_ws, size_t ws_size,
                              hipStream_t stream) {
    (void)in_sizes;
    if (n_in < 38 || ws_size < F_TOTAL * sizeof(float)) {
        int nb = (out_size + 255) / 256;
        hipLaunchKernelGGL(zero_out_kernel, dim3(nb), dim3(256), 0, stream,
                           (unsigned short*)d_out, out_size);
        return;
    }
    float* W = (float*)d_ws;
    InPtrs ptrs;
    for (int i = 0; i < 38; i++) ptrs.p[i] = d_in[i];
    int* idx1 = (int*)(W + F_IDX1);
    int* idx2 = (int*)(W + F_IDX2);
    float* wt = W + F_WT;
    float* xcat = W + F_XCAT;
    float* xcatT = W + F_XCATT;
    unsigned short* x7 = (unsigned short*)(W + F_X7);
    unsigned short* x8 = (unsigned short*)(W + F_X8);
    unsigned short* x9 = (unsigned short*)(W + F_X9);
    float* gpart = W + F_GPART;
    float* g = W + F_G;
    float* v7p = W + F_V7P;
    float* v7 = W + F_V7;
    float* wp = W + F_WP;
    int* dflag = (int*)(W + F_FLAG);
    float* xxg = W + F_XX;

    hipLaunchKernelGGL(detect_kernel, dim3(1), dim3(256), 0, stream,
                       (const unsigned short*)d_in[0], dflag);
    hipLaunchKernelGGL(prep_kernel, dim3(256), dim3(256), 0, stream, ptrs, wp, dflag);
    hipLaunchKernelGGL(knn_xyz_kernel, dim3(4096), dim3(256), 0, stream, d_in[0], dflag, idx1, wt);
    hipLaunchKernelGGL(stage1_kernel, dim3(16384), dim3(64), 0, stream, d_in[0], dflag, idx1, wt, wp, xcat, xcatT);
    hipLaunchKernelGGL(norms_kernel, dim3(32), dim3(512), 0, stream, xcat, 0, xxg);
    hipLaunchKernelGGL(knn_feat_kernel, dim3(2048), dim3(512), 0, stream, xcat, xcatT, xxg, 0, idx2);
    hipLaunchKernelGGL(stage23_kernel, dim3(16384), dim3(64), 0, stream, xcatT, idx2, wt, wp,
        (int)P_AMP2, (int)P_BMP2, (int)P_W3A, (int)P_W3B, (int)P_B3, (int)P_W4, (int)P_B4,
        0, 64, 1, xcat, xcatT);
    hipLaunchKernelGGL(norms_kernel, dim3(32), dim3(512), 0, stream, xcat, 64, xxg);
    hipLaunchKernelGGL(knn_feat_kernel, dim3(2048), dim3(512), 0, stream, xcat, xcatT, xxg, 64, idx2);
    hipLaunchKernelGGL(stage23_kernel, dim3(16384), dim3(64), 0, stream, xcatT, idx2, wt, wp,
        (int)P_AMP3, (int)P_BMP3, (int)P_W5A, (int)P_W5B, (int)P_B5, 0, 0,
        64, 128, 0, xcat, xcatT);
    hipLaunchKernelGGL((gemm_kernel<1,false,false>), dim3(16,16,8), dim3(256), 0, stream,
        (const void*)xcat, wp + P_W6, wp + P_B6, (const float*)nullptr,
        (unsigned short*)nullptr, gpart, dflag, 192, 1024, 1024);
    hipLaunchKernelGGL(gmax_reduce_kernel, dim3(4,8), dim3(256), 0, stream, gpart, g);
    hipLaunchKernelGGL(v7_part_kernel, dim3(8,8), dim3(256), 0, stream, wp, g, v7p);
    hipLaunchKernelGGL(v7_sum_kernel, dim3(8), dim3(256), 0, stream, v7p, v7);
    hipLaunchKernelGGL((gemm_kernel<0,false,true>), dim3(16,4,8), dim3(256), 0, stream,
        (const void*)xcat, wp + P_W7B, wp + P_B7, v7, x7, (float*)nullptr, dflag, 192, 256, 256);
    hipLaunchKernelGGL((gemm_kernel<0,true,false>), dim3(16,4,8), dim3(256), 0, stream,
        (const void*)x7, wp + P_W8, wp + P_B8, (const float*)nullptr, x8, (float*)nullptr, dflag, 256, 256, 256);
    hipLaunchKernelGGL((gemm_kernel<0,true,false>), dim3(16,2,8), dim3(256), 0, stream,
        (const void*)x8, wp + P_W9, wp + P_B9, (const float*)nullptr, x9, (float*)nullptr, dflag, 256, 128, 128);
    hipLaunchKernelGGL((gemm_kernel<2,true,false>), dim3(16,1,8), dim3(256), 0, stream,
        (const void*)x9, wp + P_W10, (const float*)nullptr, (const float*)nullptr,
        (unsigned short*)d_out, (float*)d_out, dflag, 128, 64, 50);
}